// Round 12
// baseline (37.625 us; speedup 1.0000x reference)
//
#include <hip/hip_runtime.h>

// Problem constants (match reference)
#define PP 32
#define SS 4
#define CC 64
#define HH 128
#define WW 128
#define NC 32
#define OO 32
#define PLANE (HH * WW)
#define NTOT (PP * SS * CC * PLANE)   // 33,554,432 elements
#define GRID 16384                    // (PP*SS*NC*OO*OO)/256

// ws: int cbase[PP*NC]; int psize[PP]
__global__ __launch_bounds__(256) void setup_kernel(
    const int* __restrict__ size_raw,
    const int* __restrict__ pix,
    const int* __restrict__ channels,
    int*       __restrict__ cbase,   // [PP*NC]
    int*       __restrict__ psize)   // [PP]
{
    const int i = blockIdx.x * 256 + threadIdx.x;   // 0..1023
    const int p = i >> 5;
    const int c = i & 31;
    const int size = size_raw[p] + OO;              // [32,128]
    const int wr = WW - size + 1;
    const int hr = HH - size + 1;
    const int pm = pix[p] % (wr * hr);
    const int offy = pm / wr;
    const int offx = pm - offy * wr;
    if (c == 0) psize[p] = size;
    const int ch = channels[p * NC + c];
    cbase[i] = (p * SS * CC + ch) * PLANE + offy * WW + offx;
}

// R10 kernel + XCD-aware block swizzle.
// Round-robin dispatch sends block i to XCD i%8; a (p,s,c) plane spans 4
// consecutive work-ids, which would land on 4 different (non-coherent) L2s,
// duplicating bin-overlap rows and shared partial lines (~23% extra HBM).
// Swizzle wid = (bid&7)*(GRID/8) + (bid>>3): each XCD owns a contiguous
// work range -> a plane's 4 blocks run on ONE XCD, temporally adjacent.
__global__ __launch_bounds__(256) void pool_kernel(
    const float* __restrict__ input,   // [P,S,C,H,W]
    const int*   __restrict__ cbase,   // [PP*NC]
    const int*   __restrict__ psize,   // [PP]
    float*       __restrict__ out)     // [P,S,NC,O,O]
{
    const int bid = blockIdx.x;
    const int wid = ((bid & 7) << 11) | (bid >> 3);   // bijective on [0,16384)
    const int idx = wid * 256 + threadIdx.x;

    const int q = idx & (OO - 1);
    const int o = (idx >> 5) & (OO - 1);
    const int c = (idx >> 10) & (NC - 1);
    const int s = (idx >> 15) & (SS - 1);
    const int p = idx >> 17;

    const int size = psize[p];                            // wave-uniform
    const int sy = (o * size) >> 5;
    const int rows = (((o + 1) * size + 31) >> 5) - sy;   // 1..5
    const int sx = (q * size) >> 5;
    const int cols = (((q + 1) * size + 31) >> 5) - sx;   // 1..5

    // absolute element offset of bin start; align to 16B
    const int abs0 = cbase[(p << 5) | c] + s * (CC * PLANE) + sy * WW + sx;
    const int sh = abs0 & 3;
    const int a0 = abs0 - sh;
    const bool need2 = (sh + cols) > 4;

    const float rscale = __builtin_amdgcn_rcpf((float)(rows * cols));

    // window masks with scale folded in: position j active iff (j-sh) in [0,cols)
    float m[8];
    #pragma unroll
    for (int j = 0; j < 8; ++j)
        m[j] = ((unsigned)(j - sh) < (unsigned)cols) ? rscale : 0.0f;

    float4 A[5], B[5];
    #pragma unroll
    for (int dy = 0; dy < 5; ++dy) {
        A[dy] = make_float4(0.f, 0.f, 0.f, 0.f);
        B[dy] = make_float4(0.f, 0.f, 0.f, 0.f);
    }
    // grouped predicated loads (no dependent VALU in between -> deep MLP)
    #pragma unroll
    for (int dy = 0; dy < 5; ++dy) {
        if (dy < rows) {
            int ro = a0 + dy * WW;
            ro = (ro > NTOT - 8) ? (NTOT - 8) : ro;       // keep in-bounds+aligned
            A[dy] = *(const float4*)(input + ro);
            if (need2) B[dy] = *(const float4*)(input + ro + 4);
        }
    }

    float acc = 0.0f;
    #pragma unroll
    for (int dy = 0; dy < 5; ++dy) {
        acc += m[0] * A[dy].x + m[1] * A[dy].y + m[2] * A[dy].z + m[3] * A[dy].w
             + m[4] * B[dy].x + m[5] * B[dy].y + m[6] * B[dy].z + m[7] * B[dy].w;
    }
    out[idx] = acc;
}

extern "C" void kernel_launch(void* const* d_in, const int* in_sizes, int n_in,
                              void* d_out, int out_size, void* d_ws, size_t ws_size,
                              hipStream_t stream) {
    const float* input    = (const float*)d_in[0];
    const int*   size_raw = (const int*)d_in[1];
    const int*   pix      = (const int*)d_in[2];
    const int*   channels = (const int*)d_in[3];
    float*       out      = (float*)d_out;

    int* cbase = (int*)d_ws;            // 1024 ints
    int* psize = cbase + PP * NC;       // 32 ints

    setup_kernel<<<4, 256, 0, stream>>>(size_raw, pix, channels, cbase, psize);

    pool_kernel<<<GRID, 256, 0, stream>>>(input, cbase, psize, out);
}

// Round 13
// 34.420 us; speedup vs baseline: 1.0931x; 1.0931x over previous
//
#include <hip/hip_runtime.h>

// Problem constants (match reference)
#define PP 32
#define SS 4
#define CC 64
#define HH 128
#define WW 128
#define NC 32
#define OO 32
#define PLANE (HH * WW)
#define NTOT (PP * SS * CC * PLANE)   // 33,554,432 elements

// ws: int cbase[PP*NC]; int psize[PP]
__global__ __launch_bounds__(256) void setup_kernel(
    const int* __restrict__ size_raw,
    const int* __restrict__ pix,
    const int* __restrict__ channels,
    int*       __restrict__ cbase,   // [PP*NC]
    int*       __restrict__ psize)   // [PP]
{
    const int i = blockIdx.x * 256 + threadIdx.x;   // 0..1023
    const int p = i >> 5;
    const int c = i & 31;
    const int size = size_raw[p] + OO;              // [32,128]
    const int wr = WW - size + 1;
    const int hr = HH - size + 1;
    const int pm = pix[p] % (wr * hr);
    const int offy = pm / wr;
    const int offx = pm - offy * wr;
    if (c == 0) psize[p] = size;
    const int ch = channels[p * NC + c];
    cbase[i] = (p * SS * CC + ch) * PLANE + offy * WW + offx;
}

// One thread per output element; predicated grouped float4 loads.
// (R10 structure — best measured: 34.4 us, ~5.8 TB/s effective = 91% of the
// 6.3 TB/s copy ceiling. XCD swizzle variant regressed (R11: 37.6) — default
// dispatch order already has the needed locality; reuse across blocks is
// negligible for this gather-style op.)
__global__ __launch_bounds__(256) void pool_kernel(
    const float* __restrict__ input,   // [P,S,C,H,W]
    const int*   __restrict__ cbase,   // [PP*NC]
    const int*   __restrict__ psize,   // [PP]
    float*       __restrict__ out)     // [P,S,NC,O,O]
{
    const int idx = blockIdx.x * 256 + threadIdx.x;
    const int q = idx & (OO - 1);
    const int o = (idx >> 5) & (OO - 1);
    const int c = (idx >> 10) & (NC - 1);
    const int s = (idx >> 15) & (SS - 1);
    const int p = idx >> 17;

    const int size = psize[p];                            // wave-uniform
    const int sy = (o * size) >> 5;
    const int rows = (((o + 1) * size + 31) >> 5) - sy;   // 1..5
    const int sx = (q * size) >> 5;
    const int cols = (((q + 1) * size + 31) >> 5) - sx;   // 1..5

    // absolute element offset of bin start; align to 16B
    const int abs0 = cbase[(p << 5) | c] + s * (CC * PLANE) + sy * WW + sx;
    const int sh = abs0 & 3;
    const int a0 = abs0 - sh;
    const bool need2 = (sh + cols) > 4;

    const float rscale = __builtin_amdgcn_rcpf((float)(rows * cols));

    // window masks with scale folded in: position j active iff (j-sh) in [0,cols)
    float m[8];
    #pragma unroll
    for (int j = 0; j < 8; ++j)
        m[j] = ((unsigned)(j - sh) < (unsigned)cols) ? rscale : 0.0f;

    float4 A[5], B[5];
    #pragma unroll
    for (int dy = 0; dy < 5; ++dy) {
        A[dy] = make_float4(0.f, 0.f, 0.f, 0.f);
        B[dy] = make_float4(0.f, 0.f, 0.f, 0.f);
    }
    // grouped predicated loads (no dependent VALU in between -> deep MLP)
    #pragma unroll
    for (int dy = 0; dy < 5; ++dy) {
        if (dy < rows) {
            int ro = a0 + dy * WW;
            ro = (ro > NTOT - 8) ? (NTOT - 8) : ro;       // keep in-bounds+aligned
            A[dy] = *(const float4*)(input + ro);
            if (need2) B[dy] = *(const float4*)(input + ro + 4);
        }
    }

    float acc = 0.0f;
    #pragma unroll
    for (int dy = 0; dy < 5; ++dy) {
        acc += m[0] * A[dy].x + m[1] * A[dy].y + m[2] * A[dy].z + m[3] * A[dy].w
             + m[4] * B[dy].x + m[5] * B[dy].y + m[6] * B[dy].z + m[7] * B[dy].w;
    }
    out[idx] = acc;
}

extern "C" void kernel_launch(void* const* d_in, const int* in_sizes, int n_in,
                              void* d_out, int out_size, void* d_ws, size_t ws_size,
                              hipStream_t stream) {
    const float* input    = (const float*)d_in[0];
    const int*   size_raw = (const int*)d_in[1];
    const int*   pix      = (const int*)d_in[2];
    const int*   channels = (const int*)d_in[3];
    float*       out      = (float*)d_out;

    int* cbase = (int*)d_ws;            // 1024 ints
    int* psize = cbase + PP * NC;       // 32 ints

    setup_kernel<<<4, 256, 0, stream>>>(size_raw, pix, channels, cbase, psize);

    const int total = PP * SS * NC * OO * OO;   // 4,194,304
    pool_kernel<<<total / 256, 256, 0, stream>>>(input, cbase, psize, out);
}